// Round 8
// baseline (350.417 us; speedup 1.0000x reference)
//
#include <hip/hip_runtime.h>
#include <hip/hip_bf16.h>

typedef unsigned short u16;
typedef unsigned int u32;
typedef __attribute__((ext_vector_type(8))) __bf16 bf16x8;
typedef __attribute__((ext_vector_type(4))) float f32x4;

#define B_ 64
#define N_ 64
#define FA_ 75
#define FP_ 14
#define C_ 128

// ---- static device scratch (fully rewritten every call) ----
__device__ float g_A0[4096 * 128];   // a0 branch, fp32 [row][feat]
__device__ float g_A1[4096 * 128];   // p2a-summed branch (agent-atomic transport)
__device__ float g_TB[4096 * 256];   // [T | Bo] per atom row, fp32
__device__ u16   g_Wf[208896];       // downstream weights in A-frag layout (bf16)
__device__ int   g_ctr16[256];       // per-(batch,row-group) completion counters

// frag-weight offsets (u16 elements); layout slot = ((mt*KS+ks)*64+lane)*8+j
#define OFF_PA0   53248
#define OFF_PA1   57344
#define OFF_AL0   73728
#define OFF_AL1   106496
#define OFF_AP1   122880
#define OFF_PP0   139264
#define OFF_PP1   143360
#define OFF_PL0T  159744
#define OFF_PL0B  176128
#define OFF_PL1   192512

__device__ __forceinline__ float bf2f(u16 a) {
    union { u32 u; float f; } v; v.u = ((u32)a) << 16; return v.f;
}
__device__ __forceinline__ u16 f2bf(float f) {
    union { float f; u32 u; } v; v.f = f;
    u32 r = v.u + 0x7fffu + ((v.u >> 16) & 1u);   // RNE
    return (u16)(r >> 16);
}
#if __has_builtin(__builtin_amdgcn_cvt_pk_bf16_f32)
__device__ __forceinline__ u32 f2bf_pk(float a, float b) {
    auto r = __builtin_amdgcn_cvt_pk_bf16_f32(a, b);
    if constexpr (sizeof(r) == 4) {
        union { decltype(r) v; u32 u; } c; c.v = r; return c.u;
    } else {
        return (u32)f2bf(a) | ((u32)f2bf(b) << 16);
    }
}
#else
__device__ __forceinline__ u32 f2bf_pk(float a, float b) {
    return (u32)f2bf(a) | ((u32)f2bf(b) << 16);
}
#endif

// per-wave input dtype detection: bf16 N(0,1) samples have sane exponents in
// the LOW halfword of each u32; fp32 mantissa bits don't. Uniform per wave.
__device__ __forceinline__ bool detect_isbf(const void* __restrict__ atom) {
    u32 wrd = ((const u32*)atom)[threadIdx.x & 63];
    u32 ex = (wrd >> 7) & 0xffu;
    unsigned long long m = __ballot(ex >= 113u && ex <= 133u);
    return __popcll(m) >= 32;
}

__device__ __forceinline__ float ldf(const void* p, size_t i, bool isbf) {
    if (isbf) return bf2f(((const u16*)p)[i]);
    return ((const float*)p)[i];
}
__device__ __forceinline__ f32x4 ldf4(const void* p, int i, bool isbf) {
    f32x4 r;
    if (isbf) {
        const u16* q = (const u16*)p + i;
        r[0] = bf2f(q[0]); r[1] = bf2f(q[1]); r[2] = bf2f(q[2]); r[3] = bf2f(q[3]);
    } else {
        r = *(const f32x4*)((const float*)p + i);
    }
    return r;
}
// pack 8 row elements k0..k0+7 (zero-padded past kmax) into bf16x8 frag word
__device__ __forceinline__ uint4 pack8(const void* p, size_t base, int kmax, int k0, bool isbf) {
    uint4 u;
    if (isbf) {
        const u16* q = (const u16*)p + base;
        u16 h[8];
#pragma unroll
        for (int j = 0; j < 8; ++j) h[j] = (k0 + j < kmax) ? q[k0 + j] : (u16)0;
        u.x = (u32)h[0] | ((u32)h[1] << 16); u.y = (u32)h[2] | ((u32)h[3] << 16);
        u.z = (u32)h[4] | ((u32)h[5] << 16); u.w = (u32)h[6] | ((u32)h[7] << 16);
    } else {
        const float* q = (const float*)p + base;
        float f[8];
#pragma unroll
        for (int j = 0; j < 8; ++j) f[j] = (k0 + j < kmax) ? q[k0 + j] : 0.f;
        u.x = f2bf_pk(f[0], f[1]); u.y = f2bf_pk(f[2], f[3]);
        u.z = f2bf_pk(f[4], f[5]); u.w = f2bf_pk(f[6], f[7]);
    }
    return u;
}
// build one A-frag (8 bf16) directly from a raw weight matrix W[K][128]:
// element j = W[rofft + k0 + j][m], zero past kmax. Bit-identical to prep path.
__device__ __forceinline__ uint4 packW8(const void* W, int kmax, int rofft,
                                        int k0, int m, bool isbf) {
    float f[8];
#pragma unroll
    for (int j = 0; j < 8; ++j) {
        int k = k0 + j;
        f[j] = (k < kmax) ? ldf(W, (size_t)(rofft + k) * 128 + m, isbf) : 0.f;
    }
    uint4 u;
    u.x = f2bf_pk(f[0], f[1]); u.y = f2bf_pk(f[2], f[3]);
    u.z = f2bf_pk(f[4], f[5]); u.w = f2bf_pk(f[6], f[7]);
    return u;
}

// ---------------- MFMA GEMM cores ----------------
__device__ __forceinline__ bf16x8 as_bf(uint4 u) {
    union { uint4 u; bf16x8 b; } cv; cv.u = u; return cv.b;
}
template<int KS, int NT>
__device__ __forceinline__ void gemm2(const u16* __restrict__ wf,
                                      const u16* __restrict__ bF,
                                      int mt0, int lane, f32x4 (&acc)[2][NT]) {
#pragma unroll
    for (int ks = 0; ks < KS; ++ks) {
        bf16x8 a0 = *(const bf16x8*)(wf + (((mt0    ) * KS + ks) * 64 + lane) * 8);
        bf16x8 a1 = *(const bf16x8*)(wf + (((mt0 + 1) * KS + ks) * 64 + lane) * 8);
#pragma unroll
        for (int nt = 0; nt < NT; ++nt) {
            bf16x8 b = *(const bf16x8*)(bF + ((nt * KS + ks) * 64 + lane) * 8);
            acc[0][nt] = __builtin_amdgcn_mfma_f32_16x16x32_bf16(a0, b, acc[0][nt], 0, 0, 0);
            acc[1][nt] = __builtin_amdgcn_mfma_f32_16x16x32_bf16(a1, b, acc[1][nt], 0, 0, 0);
        }
    }
}
// self-packing variant: A-frags built on the fly from the raw weight matrix
template<int KS, int NT>
__device__ __forceinline__ void gemm2w(const void* W, int kmax, int rofft, bool isbf,
                                       const u16* __restrict__ bF,
                                       int mt0, int lane, f32x4 (&acc)[2][NT]) {
    const int c = lane & 15, q = lane >> 4;
#pragma unroll
    for (int ks = 0; ks < KS; ++ks) {
        int k0 = ks * 32 + q * 8;
        bf16x8 a0 = as_bf(packW8(W, kmax, rofft, k0, mt0 * 16 + c, isbf));
        bf16x8 a1 = as_bf(packW8(W, kmax, rofft, k0, (mt0 + 1) * 16 + c, isbf));
#pragma unroll
        for (int nt = 0; nt < NT; ++nt) {
            bf16x8 b = *(const bf16x8*)(bF + ((nt * KS + ks) * 64 + lane) * 8);
            acc[0][nt] = __builtin_amdgcn_mfma_f32_16x16x32_bf16(a0, b, acc[0][nt], 0, 0, 0);
            acc[1][nt] = __builtin_amdgcn_mfma_f32_16x16x32_bf16(a1, b, acc[1][nt], 0, 0, 0);
        }
    }
}
// prefetched-A variants (distance-1)
template<int KS>
__device__ __forceinline__ void loadA2(const u16* __restrict__ wf, int mt0, int lane,
                                       uint4 (&aw)[2][KS]) {
#pragma unroll
    for (int ks = 0; ks < KS; ++ks) {
        aw[0][ks] = *(const uint4*)(wf + (((mt0    ) * KS + ks) * 64 + lane) * 8);
        aw[1][ks] = *(const uint4*)(wf + (((mt0 + 1) * KS + ks) * 64 + lane) * 8);
    }
}
template<int KS, int NT>
__device__ __forceinline__ void gemm2r(const uint4 (&aw)[2][KS],
                                       const u16* __restrict__ bF,
                                       int lane, f32x4 (&acc)[2][NT]) {
#pragma unroll
    for (int ks = 0; ks < KS; ++ks) {
        bf16x8 a0 = as_bf(aw[0][ks]);
        bf16x8 a1 = as_bf(aw[1][ks]);
#pragma unroll
        for (int nt = 0; nt < NT; ++nt) {
            bf16x8 b = *(const bf16x8*)(bF + ((nt * KS + ks) * 64 + lane) * 8);
            acc[0][nt] = __builtin_amdgcn_mfma_f32_16x16x32_bf16(a0, b, acc[0][nt], 0, 0, 0);
            acc[1][nt] = __builtin_amdgcn_mfma_f32_16x16x32_bf16(a1, b, acc[1][nt], 0, 0, 0);
        }
    }
}

// lgkm-only barrier: drains LDS ordering, leaves global loads/stores in flight
__device__ __forceinline__ void barrier_lgkm() {
    asm volatile("s_waitcnt lgkmcnt(0)" ::: "memory");
    __builtin_amdgcn_s_barrier();
    asm volatile("" ::: "memory");
}

// C-frag -> next-layer B-frag store (one uint2 per frag per lane)
__device__ __forceinline__ void frag_store(u16* dstF, int KSd, int nt, int mt, int lane, f32x4 v) {
    int c = lane & 15, quad = lane >> 4;
    int lp = c + 16 * ((2 * mt + (quad >> 1)) & 3);
    int ks = mt >> 1;
    uint2 u; u.x = f2bf_pk(v[0], v[1]); u.y = f2bf_pk(v[2], v[3]);
    *(uint2*)(dstF + (((nt * KSd + ks) * 64 + lp) * 8 + (quad & 1) * 4)) = u;
}

__device__ __forceinline__ void store_out4(void* outp, size_t elem, f32x4 v, bool isbf) {
    if (isbf) {
        uint2 u; u.x = f2bf_pk(v[0], v[1]); u.y = f2bf_pk(v[2], v[3]);
        *(uint2*)((u16*)outp + elem) = u;
    } else {
        *(f32x4*)((float*)outp + elem) = v;
    }
}

#define EPI_RELU_STORE(ACC, BB0, BB1, DST, NTN) do {                             \
    _Pragma("unroll") for (int ii = 0; ii < 2; ++ii) {                           \
        f32x4 bb_ = ii ? (BB1) : (BB0);                                          \
        _Pragma("unroll") for (int nt_ = 0; nt_ < NTN; ++nt_) {                  \
            f32x4 v_;                                                            \
            _Pragma("unroll") for (int r_ = 0; r_ < 4; ++r_) {                   \
                float x_ = ACC[ii][nt_][r_] + bb_[r_];                           \
                v_[r_] = x_ > 0.f ? x_ : 0.f;                                    \
            }                                                                    \
            frag_store(DST, 4, nt_, mt0 + ii, lane, v_);                         \
        }                                                                        \
    }                                                                            \
} while (0)

// ---------------- Kernel: fused weight-prep + atom pre-work (204 blocks) ----------
__global__ __launch_bounds__(256) void pre_fused(
    const void* atom,
    const void* aaW0, const void* aaW1, const void* apW0,
    const void* paW0, const void* paW1, const void* alW0, const void* alW1,
    const void* apW1, const void* ppW0, const void* ppW1,
    const void* plW0, const void* plW1,
    const void* aaB0, const void* aaB1) {
    __shared__ __align__(16) u16 sXF[2 * 3 * 64 * 8];   // 6KB (atom path)
    __shared__ __align__(16) u16 sHF[2 * 4 * 64 * 8];   // 8KB (atom path)
    const bool isbf = detect_isbf(atom);
    const int t = threadIdx.x, lane = t & 63, w = t >> 6;
    const int quad = lane >> 4;
    if (blockIdx.x == 0) {
        // reset completion counters for this call (atomic store: coherent-point write)
        __hip_atomic_store(&g_ctr16[t], 0, __ATOMIC_RELAXED, __HIP_MEMORY_SCOPE_AGENT);
    }
    if (blockIdx.x < 76) {
        // ---- weight prep path ----
        const void* srcs[10] = {paW0, paW1, alW0, alW1, apW1, ppW0, ppW1,
                                plW0, plW0, plW1};
        const int Ktab[10]  = {14, 128, 256, 128, 128, 14, 128, 128, 128, 128};
        const int KStab[10] = {1, 4, 8, 4, 4, 1, 4, 4, 4, 4};
        const int rofft[10] = {0, 0, 0, 0, 0, 0, 0, 0, 128, 0};
        const int baset[10] = {OFF_PA0, OFF_PA1, OFF_AL0, OFF_AL1, OFF_AP1,
                               OFF_PP0, OFF_PP1, OFF_PL0T, OFF_PL0B, OFF_PL1};
        int gid = blockIdx.x * 256 + t;
        int j = 0, s = gid;
        while (j < 10 && s >= KStab[j] * 512) { s -= KStab[j] * 512; ++j; }
        if (j >= 10) return;
        int ln = s & 63, rest = s >> 6;
        int ks = rest % KStab[j], mt = rest / KStab[j];
        int m = mt * 16 + (ln & 15), q = ln >> 4;
        float f[8];
#pragma unroll
        for (int jj = 0; jj < 8; ++jj) {
            int k = ks * 32 + q * 8 + jj;
            f[jj] = (k < Ktab[j]) ? ldf(srcs[j], (size_t)(rofft[j] + k) * 128 + m, isbf) : 0.f;
        }
        uint4 u;
        u.x = f2bf_pk(f[0], f[1]); u.y = f2bf_pk(f[2], f[3]);
        u.z = f2bf_pk(f[4], f[5]); u.w = f2bf_pk(f[6], f[7]);
        *(uint4*)&g_Wf[(size_t)baset[j] + (size_t)s * 8] = u;
        return;
    }
    // ---- atom_pre path ----
    const int r0g = (blockIdx.x - 76) * 32;
    for (int s = t; s < 2 * 3 * 64; s += 256) {
        int lane_s = s & 63, rest = s >> 6;
        int ks = rest % 3, nt = rest / 3;
        int n = nt * 16 + (lane_s & 15), q = lane_s >> 4;
        *(uint4*)&sXF[s * 8] = pack8(atom, (size_t)(r0g + n) * FA_, FA_, ks * 32 + q * 8, isbf);
    }
    __syncthreads();
    const int mt0 = 2 * w;
    {
        f32x4 bb0 = ldf4(aaB0, mt0 * 16 + quad * 4, isbf);
        f32x4 bb1 = ldf4(aaB0, (mt0 + 1) * 16 + quad * 4, isbf);
        f32x4 acc[2][2];
#pragma unroll
        for (int ii = 0; ii < 2; ++ii)
#pragma unroll
            for (int nt = 0; nt < 2; ++nt) acc[ii][nt] = (f32x4){0.f, 0.f, 0.f, 0.f};
        gemm2w<3, 2>(aaW0, 75, 0, isbf, sXF, mt0, lane, acc);
        EPI_RELU_STORE(acc, bb0, bb1, sHF, 2);
    }
    __syncthreads();
    {
        f32x4 bb0 = ldf4(aaB1, mt0 * 16 + quad * 4, isbf);
        f32x4 bb1 = ldf4(aaB1, (mt0 + 1) * 16 + quad * 4, isbf);
        f32x4 acc[2][2];
#pragma unroll
        for (int ii = 0; ii < 2; ++ii)
#pragma unroll
            for (int nt = 0; nt < 2; ++nt) acc[ii][nt] = (f32x4){0.f, 0.f, 0.f, 0.f};
        gemm2w<4, 2>(aaW1, 128, 0, isbf, sHF, mt0, lane, acc);
        int c = lane & 15;
#pragma unroll
        for (int ii = 0; ii < 2; ++ii) {
            int mt = mt0 + ii;
            f32x4 bb = ii ? bb1 : bb0;
#pragma unroll
            for (int nt = 0; nt < 2; ++nt) {
                f32x4 v;
#pragma unroll
                for (int r = 0; r < 4; ++r) { float x = acc[ii][nt][r] + bb[r]; v[r] = x > 0.f ? x : 0.f; }
                *(f32x4*)&g_A0[(size_t)(r0g + nt * 16 + c) * 128 + mt * 16 + quad * 4] = v;
            }
        }
    }
    {
        f32x4 accT[2][2], accB[2][2];
#pragma unroll
        for (int ii = 0; ii < 2; ++ii)
#pragma unroll
            for (int nt = 0; nt < 2; ++nt) { accT[ii][nt] = (f32x4){0.f,0.f,0.f,0.f}; accB[ii][nt] = (f32x4){0.f,0.f,0.f,0.f}; }
        gemm2w<3, 2>(apW0, 75, 0, isbf, sXF, mt0, lane, accT);
        gemm2w<3, 2>(apW0, 75, 75, isbf, sXF, mt0, lane, accB);
        int c = lane & 15;
#pragma unroll
        for (int ii = 0; ii < 2; ++ii) {
            int mt = mt0 + ii;
#pragma unroll
            for (int nt = 0; nt < 2; ++nt) {
                size_t row = (size_t)(r0g + nt * 16 + c);
                *(f32x4*)&g_TB[row * 256 + mt * 16 + quad * 4] = accT[ii][nt];
                *(f32x4*)&g_TB[row * 256 + 128 + mt * 16 + quad * 4] = accB[ii][nt];
            }
        }
    }
}

// ---------------- Kernel: fused pair branch + PairToAtom + atom_layer -------------
// R7 pair_fused (lgkm barriers + distance-1 prefetch + setprio) + atom_layer fold
// via pure atomic message-passing: g_A1 travels through AGENT-scope relaxed
// atomics (device-coherent, no fences / no L2 writeback-invalidate — the R2
// mistake). 16th finisher of each (batch, 16-row group) runs atom_layer inline.
__global__ __launch_bounds__(256, 3) void pair_fused(
    const void* __restrict__ atom,
    const void* __restrict__ pairx,
    const void* __restrict__ apB0, const void* __restrict__ apB1,
    const void* __restrict__ ppB0, const void* __restrict__ ppB1,
    const void* __restrict__ plB0, const void* __restrict__ plB1,
    const void* __restrict__ paB0, const void* __restrict__ paB1,
    const void* __restrict__ alB0, const void* __restrict__ alB1,
    void* __restrict__ out) {
    __shared__ __align__(16) u16 sX1[4 * 4 * 64 * 8];   // 16KB  H0 -> Hp -> Hl -> AL stage
    __shared__ __align__(16) u16 sX2[4 * 4 * 64 * 8];   // 16KB  H1 -> HpA -> AL hidden
    __shared__ __align__(16) u16 sR [4 * 4 * 64 * 8];   // 16KB  P0 -> P1
    __shared__ __align__(16) u16 sPr[4 * 1 * 64 * 8];   // 4KB   pair_x frags
    __shared__ int sLast;
    const bool isbf = detect_isbf(atom);
    const int t = threadIdx.x, lane = t & 63, w = t >> 6;
    const int quad = lane >> 4, c = lane & 15;
    const int bx = blockIdx.x;
    const int b = bx >> 6, i = bx & 63;
    const int trow = b * 64;
    const size_t prow0 = (size_t)b * 4096 + (size_t)i * 64;
    const int mt0 = 2 * w;

    // ---- stage (no barriers yet): Pr frags + H0/H1 built from registers ----
    {
        int lane_s = t & 63, nt = t >> 6;
        int n = nt * 16 + (lane_s & 15), q = lane_s >> 4;
        *(uint4*)&sPr[t * 8] = pack8(pairx, (prow0 + n) * FP_, FP_, q * 8, isbf);
    }
    {
        const int ksg = t >> 6;               // this thread's ks segment
        const int k0 = ksg * 32 + quad * 8;   // fixed 8-wide k window
        const int rc = c;                     // row-class within each 16-row group
        const float* TBi = &g_TB[(size_t)(trow + i) * 256 + k0];
        f32x4 t0 = *(const f32x4*)TBi,        t1 = *(const f32x4*)(TBi + 4);
        f32x4 o0 = *(const f32x4*)(TBi + 128), o1 = *(const f32x4*)(TBi + 132);
        f32x4 b0a = ldf4(apB0, k0, isbf), b0b = ldf4(apB0, k0 + 4, isbf);
        float Tip[8], Bip[8];
#pragma unroll
        for (int r = 0; r < 4; ++r) {
            Tip[r] = t0[r] + b0a[r]; Tip[4 + r] = t1[r] + b0b[r];
            Bip[r] = o0[r] + b0a[r]; Bip[4 + r] = o1[r] + b0b[r];
        }
#pragma unroll
        for (int nt = 0; nt < 4; ++nt) {
            int n = nt * 16 + rc;
            const float* Bj = &g_TB[(size_t)(trow + n) * 256 + k0];
            f32x4 j0 = *(const f32x4*)Bj,        j1 = *(const f32x4*)(Bj + 4);
            f32x4 j2 = *(const f32x4*)(Bj + 128), j3 = *(const f32x4*)(Bj + 132);
            float v0[8], v1[8];
#pragma unroll
            for (int r = 0; r < 4; ++r) {
                float x0 = Tip[r] + j2[r];      v0[r]     = x0 > 0.f ? x0 : 0.f;  // H0
                float x1 = Tip[4 + r] + j3[r];  v0[4 + r] = x1 > 0.f ? x1 : 0.f;
                float y0 = j0[r] + Bip[r];      v1[r]     = y0 > 0.f ? y0 : 0.f;  // H1
                float y1 = j1[r] + Bip[4 + r];  v1[4 + r] = y1 > 0.f ? y1 : 0.f;
            }
            uint4 u0, u1;
            u0.x = f2bf_pk(v0[0], v0[1]); u0.y = f2bf_pk(v0[2], v0[3]);
            u0.z = f2bf_pk(v0[4], v0[5]); u0.w = f2bf_pk(v0[6], v0[7]);
            u1.x = f2bf_pk(v1[0], v1[1]); u1.y = f2bf_pk(v1[2], v1[3]);
            u1.z = f2bf_pk(v1[4], v1[5]); u1.w = f2bf_pk(v1[6], v1[7]);
            int slot = ((nt * 4 + ksg) * 64 + lane) * 8;
            *(uint4*)&sX1[slot] = u0;
            *(uint4*)&sX2[slot] = u1;
        }
    }
    // prefetch phase-C weights (independent of LDS; overlaps barrier)
    uint4 aAP1[2][4]; loadA2<4>(g_Wf + OFF_AP1, mt0, lane, aAP1);
    barrier_lgkm();
    // ---- phase C ----
    {
        f32x4 bb0 = ldf4(apB1, mt0 * 16 + quad * 4, isbf);
        f32x4 bb1 = ldf4(apB1, (mt0 + 1) * 16 + quad * 4, isbf);
        f32x4 aA[2][4], aB[2][4];
#pragma unroll
        for (int ii = 0; ii < 2; ++ii)
#pragma unroll
            for (int nt = 0; nt < 4; ++nt) { aA[ii][nt] = (f32x4){0.f,0.f,0.f,0.f}; aB[ii][nt] = (f32x4){0.f,0.f,0.f,0.f}; }
        __builtin_amdgcn_s_setprio(1);
        gemm2r<4, 4>(aAP1, sX1, lane, aA);
        gemm2r<4, 4>(aAP1, sX2, lane, aB);
        __builtin_amdgcn_s_setprio(0);
#pragma unroll
        for (int ii = 0; ii < 2; ++ii) {
            int mt = mt0 + ii;
            f32x4 bb = ii ? bb1 : bb0;
#pragma unroll
            for (int nt = 0; nt < 4; ++nt) {
                f32x4 v;
#pragma unroll
                for (int r = 0; r < 4; ++r) {
                    float x = aA[ii][nt][r] + bb[r];
                    float y = aB[ii][nt][r] + bb[r];
                    v[r] = (x > 0.f ? x : 0.f) + (y > 0.f ? y : 0.f);
                }
                frag_store(sR, 4, nt, mt, lane, v);
            }
        }
    }
    f32x4 aH[2][4], aPA[2][4];
    {
        uint4 aPP0[2][1]; loadA2<1>(g_Wf + OFF_PP0, mt0, lane, aPP0);
        uint4 aPA0[2][1]; loadA2<1>(g_Wf + OFF_PA0, mt0, lane, aPA0);
#pragma unroll
        for (int ii = 0; ii < 2; ++ii)
#pragma unroll
            for (int nt = 0; nt < 4; ++nt) { aH[ii][nt] = (f32x4){0.f,0.f,0.f,0.f}; aPA[ii][nt] = (f32x4){0.f,0.f,0.f,0.f}; }
        gemm2r<1, 4>(aPP0, sPr, lane, aH);
        gemm2r<1, 4>(aPA0, sPr, lane, aPA);
    }
    // prefetch phase-D weights
    uint4 aPL0T[2][4]; loadA2<4>(g_Wf + OFF_PL0T, mt0, lane, aPL0T);
    barrier_lgkm();
    // ---- phase D ----
    f32x4 C3[2][4];
#pragma unroll
    for (int ii = 0; ii < 2; ++ii)
#pragma unroll
        for (int nt = 0; nt < 4; ++nt) C3[ii][nt] = (f32x4){0.f, 0.f, 0.f, 0.f};
    __builtin_amdgcn_s_setprio(1);
    gemm2r<4, 4>(aPL0T, sR, lane, C3);
    __builtin_amdgcn_s_setprio(0);
    {
        f32x4 bb0 = ldf4(ppB0, mt0 * 16 + quad * 4, isbf);
        f32x4 bb1 = ldf4(ppB0, (mt0 + 1) * 16 + quad * 4, isbf);
        EPI_RELU_STORE(aH, bb0, bb1, sX1, 4);
    }
    {
        f32x4 bb0 = ldf4(paB0, mt0 * 16 + quad * 4, isbf);
        f32x4 bb1 = ldf4(paB0, (mt0 + 1) * 16 + quad * 4, isbf);
        EPI_RELU_STORE(aPA, bb0, bb1, sX2, 4);
    }
    // prefetch phase-E weights
    uint4 aPP1[2][4]; loadA2<4>(g_Wf + OFF_PP1, mt0, lane, aPP1);
    uint4 aPA1[2][4]; loadA2<4>(g_Wf + OFF_PA1, mt0, lane, aPA1);
    barrier_lgkm();
    // ---- phase E ----
    {
        f32x4 aP[2][4], aA1[2][4];
#pragma unroll
        for (int ii = 0; ii < 2; ++ii)
#pragma unroll
            for (int nt = 0; nt < 4; ++nt) { aP[ii][nt] = (f32x4){0.f,0.f,0.f,0.f}; aA1[ii][nt] = (f32x4){0.f,0.f,0.f,0.f}; }
        __builtin_amdgcn_s_setprio(1);
        gemm2r<4, 4>(aPP1, sX1, lane, aP);
        gemm2r<4, 4>(aPA1, sX2, lane, aA1);
        __builtin_amdgcn_s_setprio(0);
        {
            f32x4 pb0 = ldf4(paB1, mt0 * 16 + quad * 4, isbf);
            f32x4 pb1 = ldf4(paB1, (mt0 + 1) * 16 + quad * 4, isbf);
#pragma unroll
            for (int ii = 0; ii < 2; ++ii) {
                int mt = mt0 + ii;
                f32x4 bb = ii ? pb1 : pb0;
                f32x4 ssum = (f32x4){0.f, 0.f, 0.f, 0.f};
#pragma unroll
                for (int nt = 0; nt < 4; ++nt)
#pragma unroll
                    for (int r = 0; r < 4; ++r) {
                        float x = aA1[ii][nt][r] + bb[r];
                        ssum[r] += (x > 0.f ? x : 0.f);
                    }
#pragma unroll
                for (int m = 1; m < 16; m <<= 1)
#pragma unroll
                    for (int r = 0; r < 4; ++r) ssum[r] += __shfl_xor(ssum[r], m, 64);
                if ((lane & 15) == 0) {
                    float* dst = &g_A1[(size_t)bx * 128 + mt * 16 + quad * 4];
#pragma unroll
                    for (int r = 0; r < 4; ++r)
                        __hip_atomic_store(dst + r, ssum[r], __ATOMIC_RELAXED,
                                           __HIP_MEMORY_SCOPE_AGENT);
                }
            }
        }
        f32x4 bb0 = ldf4(ppB1, mt0 * 16 + quad * 4, isbf);
        f32x4 bb1 = ldf4(ppB1, (mt0 + 1) * 16 + quad * 4, isbf);
        EPI_RELU_STORE(aP, bb0, bb1, sR, 4);
    }
    // prefetch phase-F weights
    uint4 aPL0B[2][4]; loadA2<4>(g_Wf + OFF_PL0B, mt0, lane, aPL0B);
    barrier_lgkm();
    // ---- phase F ----
    __builtin_amdgcn_s_setprio(1);
    gemm2r<4, 4>(aPL0B, sR, lane, C3);
    __builtin_amdgcn_s_setprio(0);
    {
        f32x4 bb0 = ldf4(plB0, mt0 * 16 + quad * 4, isbf);
        f32x4 bb1 = ldf4(plB0, (mt0 + 1) * 16 + quad * 4, isbf);
        EPI_RELU_STORE(C3, bb0, bb1, sX1, 4);
    }
    // prefetch phase-G weights
    uint4 aPL1[2][4]; loadA2<4>(g_Wf + OFF_PL1, mt0, lane, aPL1);
    barrier_lgkm();
    // ---- phase G ----
    {
        f32x4 bb0 = ldf4(plB1, mt0 * 16 + quad * 4, isbf);
        f32x4 bb1 = ldf4(plB1, (mt0 + 1) * 16 + quad * 4, isbf);
        f32x4 aO[2][4];
#pragma unroll
        for (int ii = 0; ii < 2; ++ii)
#pragma unroll
            for (int nt = 0; nt < 4; ++nt) aO[ii][nt] = (f32x4){0.f, 0.f, 0.f, 0.f};
        __builtin_amdgcn_s_setprio(1);
        gemm2r<4, 4>(aPL1, sX1, lane, aO);
        __builtin_amdgcn_s_setprio(0);
        const size_t NA = (size_t)B_ * N_ * C_;   // 524288
#pragma unroll
        for (int ii = 0; ii < 2; ++ii) {
            int mt = mt0 + ii;
            f32x4 bb = ii ? bb1 : bb0;
#pragma unroll
            for (int nt = 0; nt < 4; ++nt) {
                f32x4 v;
#pragma unroll
                for (int r = 0; r < 4; ++r) { float x = aO[ii][nt][r] + bb[r]; v[r] = x > 0.f ? x : 0.f; }
                store_out4(out, NA + (prow0 + nt * 16 + c) * 128 + mt * 16 + quad * 4, v, isbf);
            }
        }
    }
    // ---- folded atom_layer: pure-atomic handoff, no fences / cache maintenance ---
    // drain this thread's atomic g_A1 stores to the coherent point, then count.
    asm volatile("s_waitcnt vmcnt(0)" ::: "memory");
    __syncthreads();
    if (t == 0) {
        int done = __hip_atomic_fetch_add(&g_ctr16[(b << 2) + (i >> 4)], 1,
                                          __ATOMIC_RELAXED, __HIP_MEMORY_SCOPE_AGENT);
        sLast = (done == 15) ? 1 : 0;
    }
    __syncthreads();
    if (sLast) {
        const int r0g = b * 64 + (i >> 4) * 16;    // global atom-row base of group
        for (int s = t; s < 8 * 64; s += 256) {
            int lane_s = s & 63, ks = s >> 6;
            int n = lane_s & 15, q = lane_s >> 4;
            int k0 = ks * 32 + q * 8;
            f32x4 f0, f1;
            if (k0 < 128) {
                const float* src = &g_A0[(size_t)(r0g + n) * 128 + k0];
                f0 = *(const f32x4*)src; f1 = *(const f32x4*)(src + 4);
            } else {
                const float* src = &g_A1[(size_t)(r0g + n) * 128 + (k0 - 128)];
#pragma unroll
                for (int r = 0; r < 4; ++r) {
                    f0[r] = __hip_atomic_load(src + r, __ATOMIC_RELAXED,
                                              __HIP_MEMORY_SCOPE_AGENT);
                    f1[r] = __hip_atomic_load(src + 4 + r, __ATOMIC_RELAXED,
                                              __HIP_MEMORY_SCOPE_AGENT);
                }
            }
            uint4 u;
            u.x = f2bf_pk(f0[0], f0[1]); u.y = f2bf_pk(f0[2], f0[3]);
            u.z = f2bf_pk(f1[0], f1[1]); u.w = f2bf_pk(f1[2], f1[3]);
            *(uint4*)&sX1[s * 8] = u;
        }
        __syncthreads();
        {
            f32x4 bb0 = ldf4(alB0, mt0 * 16 + quad * 4, isbf);
            f32x4 bb1 = ldf4(alB0, (mt0 + 1) * 16 + quad * 4, isbf);
            f32x4 acc[2][1];
#pragma unroll
            for (int ii = 0; ii < 2; ++ii) acc[ii][0] = (f32x4){0.f, 0.f, 0.f, 0.f};
            gemm2<8, 1>(g_Wf + OFF_AL0, sX1, mt0, lane, acc);
            EPI_RELU_STORE(acc, bb0, bb1, sX2, 1);
        }
        __syncthreads();
        {
            f32x4 bb0 = ldf4(alB1, mt0 * 16 + quad * 4, isbf);
            f32x4 bb1 = ldf4(alB1, (mt0 + 1) * 16 + quad * 4, isbf);
            f32x4 acc[2][1];
#pragma unroll
            for (int ii = 0; ii < 2; ++ii) acc[ii][0] = (f32x4){0.f, 0.f, 0.f, 0.f};
            gemm2<4, 1>(g_Wf + OFF_AL1, sX2, mt0, lane, acc);
#pragma unroll
            for (int ii = 0; ii < 2; ++ii) {
                int mt = mt0 + ii;
                f32x4 bb = ii ? bb1 : bb0;
                f32x4 v;
#pragma unroll
                for (int r = 0; r < 4; ++r) { float x = acc[ii][0][r] + bb[r]; v[r] = x > 0.f ? x : 0.f; }
                store_out4(out, (size_t)(r0g + c) * 128 + mt * 16 + quad * 4, v, isbf);
            }
        }
    }
}

extern "C" void kernel_launch(void* const* d_in, const int* in_sizes, int n_in,
                              void* d_out, int out_size, void* d_ws, size_t ws_size,
                              hipStream_t stream) {
    const void* atom  = d_in[0];
    const void* pairx = d_in[1];
    const void* aaW0 = d_in[2];  const void* aaB0 = d_in[3];
    const void* aaW1 = d_in[4];  const void* aaB1 = d_in[5];
    const void* paW0 = d_in[6];  const void* paB0 = d_in[7];
    const void* paW1 = d_in[8];  const void* paB1 = d_in[9];
    const void* alW0 = d_in[10]; const void* alB0 = d_in[11];
    const void* alW1 = d_in[12]; const void* alB1 = d_in[13];
    const void* apW0 = d_in[14]; const void* apB0 = d_in[15];
    const void* apW1 = d_in[16]; const void* apB1 = d_in[17];
    const void* ppW0 = d_in[18]; const void* ppB0 = d_in[19];
    const void* ppW1 = d_in[20]; const void* ppB1 = d_in[21];
    const void* plW0 = d_in[22]; const void* plB0 = d_in[23];
    const void* plW1 = d_in[24]; const void* plB1 = d_in[25];
    (void)d_ws; (void)ws_size; (void)in_sizes; (void)n_in; (void)out_size;

    pre_fused<<<204, 256, 0, stream>>>(atom, aaW0, aaW1, apW0, paW0, paW1,
                                       alW0, alW1, apW1, ppW0, ppW1, plW0, plW1,
                                       aaB0, aaB1);
    pair_fused<<<4096, 256, 0, stream>>>(atom, pairx, apB0, apB1, ppB0, ppB1,
                                         plB0, plB1, paB0, paB1, alB0, alB1, d_out);
}

// Round 9
// 288.881 us; speedup vs baseline: 1.2130x; 1.2130x over previous
//
#include <hip/hip_runtime.h>
#include <hip/hip_bf16.h>

typedef unsigned short u16;
typedef unsigned int u32;
typedef __attribute__((ext_vector_type(8))) __bf16 bf16x8;
typedef __attribute__((ext_vector_type(4))) float f32x4;

#define B_ 64
#define N_ 64
#define FA_ 75
#define FP_ 14
#define C_ 128

// ---- static device scratch (fully rewritten every call) ----
__device__ float g_A0[4096 * 128];   // a0 branch, fp32 [row][feat]
__device__ float g_A1[4096 * 128];   // p2a-summed branch, fp32 (written by pair_fused)
__device__ float g_TB[4096 * 256];   // [T | Bo] per atom row, fp32
__device__ u16   g_Wf[208896];       // all weights in A-fragment layout (bf16)

// frag-weight offsets (u16 elements); layout slot = ((mt*KS+ks)*64+lane)*8+j
#define OFF_AA0   0
#define OFF_AA1   12288
#define OFF_APT   28672
#define OFF_APB   40960
#define OFF_PA0   53248
#define OFF_PA1   57344
#define OFF_AL0   73728
#define OFF_AL1   106496
#define OFF_AP1   122880
#define OFF_PP0   139264
#define OFF_PP1   143360
#define OFF_PL0T  159744
#define OFF_PL0B  176128
#define OFF_PL1   192512

__device__ __forceinline__ float bf2f(u16 a) {
    union { u32 u; float f; } v; v.u = ((u32)a) << 16; return v.f;
}
__device__ __forceinline__ u16 f2bf(float f) {
    union { float f; u32 u; } v; v.f = f;
    u32 r = v.u + 0x7fffu + ((v.u >> 16) & 1u);   // RNE
    return (u16)(r >> 16);
}
#if __has_builtin(__builtin_amdgcn_cvt_pk_bf16_f32)
__device__ __forceinline__ u32 f2bf_pk(float a, float b) {
    auto r = __builtin_amdgcn_cvt_pk_bf16_f32(a, b);
    if constexpr (sizeof(r) == 4) {
        union { decltype(r) v; u32 u; } c; c.v = r; return c.u;
    } else {
        return (u32)f2bf(a) | ((u32)f2bf(b) << 16);
    }
}
#else
__device__ __forceinline__ u32 f2bf_pk(float a, float b) {
    return (u32)f2bf(a) | ((u32)f2bf(b) << 16);
}
#endif

// per-wave input dtype detection: bf16 N(0,1) samples have sane exponents in
// the LOW halfword of each u32; fp32 mantissa bits don't. Uniform per wave.
__device__ __forceinline__ bool detect_isbf(const void* __restrict__ atom) {
    u32 wrd = ((const u32*)atom)[threadIdx.x & 63];
    u32 ex = (wrd >> 7) & 0xffu;
    unsigned long long m = __ballot(ex >= 113u && ex <= 133u);
    return __popcll(m) >= 32;
}

__device__ __forceinline__ float ldf(const void* p, size_t i, bool isbf) {
    if (isbf) return bf2f(((const u16*)p)[i]);
    return ((const float*)p)[i];
}
__device__ __forceinline__ f32x4 ldf4(const void* p, int i, bool isbf) {
    f32x4 r;
    if (isbf) {
        const u16* q = (const u16*)p + i;
        r[0] = bf2f(q[0]); r[1] = bf2f(q[1]); r[2] = bf2f(q[2]); r[3] = bf2f(q[3]);
    } else {
        r = *(const f32x4*)((const float*)p + i);
    }
    return r;
}
// pack 8 row elements k0..k0+7 (zero-padded past kmax) into bf16x8 frag word
__device__ __forceinline__ uint4 pack8(const void* p, size_t base, int kmax, int k0, bool isbf) {
    uint4 u;
    if (isbf) {
        const u16* q = (const u16*)p + base;
        u16 h[8];
#pragma unroll
        for (int j = 0; j < 8; ++j) h[j] = (k0 + j < kmax) ? q[k0 + j] : (u16)0;
        u.x = (u32)h[0] | ((u32)h[1] << 16); u.y = (u32)h[2] | ((u32)h[3] << 16);
        u.z = (u32)h[4] | ((u32)h[5] << 16); u.w = (u32)h[6] | ((u32)h[7] << 16);
    } else {
        const float* q = (const float*)p + base;
        float f[8];
#pragma unroll
        for (int j = 0; j < 8; ++j) f[j] = (k0 + j < kmax) ? q[k0 + j] : 0.f;
        u.x = f2bf_pk(f[0], f[1]); u.y = f2bf_pk(f[2], f[3]);
        u.z = f2bf_pk(f[4], f[5]); u.w = f2bf_pk(f[6], f[7]);
    }
    return u;
}

// ---------------- weight prep: global [K][128] -> A-frag layout ----------------
__global__ __launch_bounds__(256) void prep_w(
    const void* atom,
    const void* aaW0, const void* aaW1, const void* apW0,
    const void* paW0, const void* paW1, const void* alW0, const void* alW1,
    const void* apW1, const void* ppW0, const void* ppW1,
    const void* plW0, const void* plW1) {
    const bool isbf = detect_isbf(atom);
    const void* srcs[14] = {aaW0, aaW1, apW0, apW0, paW0, paW1, alW0, alW1,
                            apW1, ppW0, ppW1, plW0, plW0, plW1};
    const int Ktab[14]  = {75, 128, 75, 75, 14, 128, 256, 128, 128, 14, 128, 128, 128, 128};
    const int KStab[14] = {3, 4, 3, 3, 1, 4, 8, 4, 4, 1, 4, 4, 4, 4};
    const int rofft[14] = {0, 0, 0, 75, 0, 0, 0, 0, 0, 0, 0, 0, 128, 0};
    const int baset[14] = {OFF_AA0, OFF_AA1, OFF_APT, OFF_APB, OFF_PA0, OFF_PA1,
                           OFF_AL0, OFF_AL1, OFF_AP1, OFF_PP0, OFF_PP1,
                           OFF_PL0T, OFF_PL0B, OFF_PL1};
    int gid = blockIdx.x * 256 + threadIdx.x;
    int j = 0, s = gid;
    while (j < 14 && s >= KStab[j] * 512) { s -= KStab[j] * 512; ++j; }
    if (j >= 14) return;
    int lane = s & 63, rest = s >> 6;
    int ks = rest % KStab[j], mt = rest / KStab[j];
    int m = mt * 16 + (lane & 15), q = lane >> 4;
    float f[8];
#pragma unroll
    for (int jj = 0; jj < 8; ++jj) {
        int k = ks * 32 + q * 8 + jj;
        f[jj] = (k < Ktab[j]) ? ldf(srcs[j], (size_t)(rofft[j] + k) * 128 + m, isbf) : 0.f;
    }
    uint4 u;
    u.x = f2bf_pk(f[0], f[1]); u.y = f2bf_pk(f[2], f[3]);
    u.z = f2bf_pk(f[4], f[5]); u.w = f2bf_pk(f[6], f[7]);
    *(uint4*)&g_Wf[(size_t)baset[j] + (size_t)s * 8] = u;
}

// ---------------- MFMA GEMM cores ----------------
__device__ __forceinline__ bf16x8 as_bf(uint4 u) {
    union { uint4 u; bf16x8 b; } cv; cv.u = u; return cv.b;
}
template<int KS, int NT>
__device__ __forceinline__ void gemm2(const u16* __restrict__ wf,
                                      const u16* __restrict__ bF,
                                      int mt0, int lane, f32x4 (&acc)[2][NT]) {
#pragma unroll
    for (int ks = 0; ks < KS; ++ks) {
        bf16x8 a0 = *(const bf16x8*)(wf + (((mt0    ) * KS + ks) * 64 + lane) * 8);
        bf16x8 a1 = *(const bf16x8*)(wf + (((mt0 + 1) * KS + ks) * 64 + lane) * 8);
#pragma unroll
        for (int nt = 0; nt < NT; ++nt) {
            bf16x8 b = *(const bf16x8*)(bF + ((nt * KS + ks) * 64 + lane) * 8);
            acc[0][nt] = __builtin_amdgcn_mfma_f32_16x16x32_bf16(a0, b, acc[0][nt], 0, 0, 0);
            acc[1][nt] = __builtin_amdgcn_mfma_f32_16x16x32_bf16(a1, b, acc[1][nt], 0, 0, 0);
        }
    }
}
// prefetched-A variants (distance-1: loads issued just before the barrier that
// precedes their consuming phase; arrays die right after the gemm).
template<int KS>
__device__ __forceinline__ void loadA2(const u16* __restrict__ wf, int mt0, int lane,
                                       uint4 (&aw)[2][KS]) {
#pragma unroll
    for (int ks = 0; ks < KS; ++ks) {
        aw[0][ks] = *(const uint4*)(wf + (((mt0    ) * KS + ks) * 64 + lane) * 8);
        aw[1][ks] = *(const uint4*)(wf + (((mt0 + 1) * KS + ks) * 64 + lane) * 8);
    }
}
template<int KS, int NT>
__device__ __forceinline__ void gemm2r(const uint4 (&aw)[2][KS],
                                       const u16* __restrict__ bF,
                                       int lane, f32x4 (&acc)[2][NT]) {
#pragma unroll
    for (int ks = 0; ks < KS; ++ks) {
        bf16x8 a0 = as_bf(aw[0][ks]);
        bf16x8 a1 = as_bf(aw[1][ks]);
#pragma unroll
        for (int nt = 0; nt < NT; ++nt) {
            bf16x8 b = *(const bf16x8*)(bF + ((nt * KS + ks) * 64 + lane) * 8);
            acc[0][nt] = __builtin_amdgcn_mfma_f32_16x16x32_bf16(a0, b, acc[0][nt], 0, 0, 0);
            acc[1][nt] = __builtin_amdgcn_mfma_f32_16x16x32_bf16(a1, b, acc[1][nt], 0, 0, 0);
        }
    }
}

// lgkm-only barrier: drains LDS ordering, leaves global loads/stores in flight
// (validated pattern, learn_hip m195-m204). No intra-kernel cross-wave global
// dataflow exists in these kernels, so vmcnt need not drain at barriers.
__device__ __forceinline__ void barrier_lgkm() {
    asm volatile("s_waitcnt lgkmcnt(0)" ::: "memory");
    __builtin_amdgcn_s_barrier();
    asm volatile("" ::: "memory");
}

// C-frag -> next-layer B-frag store (one uint2 per frag per lane)
__device__ __forceinline__ void frag_store(u16* dstF, int KSd, int nt, int mt, int lane, f32x4 v) {
    int c = lane & 15, quad = lane >> 4;
    int lp = c + 16 * ((2 * mt + (quad >> 1)) & 3);
    int ks = mt >> 1;
    uint2 u; u.x = f2bf_pk(v[0], v[1]); u.y = f2bf_pk(v[2], v[3]);
    *(uint2*)(dstF + (((nt * KSd + ks) * 64 + lp) * 8 + (quad & 1) * 4)) = u;
}

__device__ __forceinline__ void store_out4(void* outp, size_t elem, f32x4 v, bool isbf) {
    if (isbf) {
        uint2 u; u.x = f2bf_pk(v[0], v[1]); u.y = f2bf_pk(v[2], v[3]);
        *(uint2*)((u16*)outp + elem) = u;
    } else {
        *(f32x4*)((float*)outp + elem) = v;
    }
}

#define EPI_RELU_STORE(ACC, BB0, BB1, DST, NTN) do {                             \
    _Pragma("unroll") for (int ii = 0; ii < 2; ++ii) {                           \
        f32x4 bb_ = ii ? (BB1) : (BB0);                                          \
        _Pragma("unroll") for (int nt_ = 0; nt_ < NTN; ++nt_) {                  \
            f32x4 v_;                                                            \
            _Pragma("unroll") for (int r_ = 0; r_ < 4; ++r_) {                   \
                float x_ = ACC[ii][nt_][r_] + bb_[r_];                           \
                v_[r_] = x_ > 0.f ? x_ : 0.f;                                    \
            }                                                                    \
            frag_store(DST, 4, nt_, mt0 + ii, lane, v_);                         \
        }                                                                        \
    }                                                                            \
} while (0)

// ---------------- Kernel: atom branch pre-work (256 blocks, 16 rows each) ---------
// 2x blocks vs the 128x32-row version: every CU active (was 0.5 blocks/CU).
// lgkm barriers + distance-1 weight prefetch, same as pair_fused.
__global__ __launch_bounds__(256) void atom_pre(
    const void* __restrict__ atom,
    const void* __restrict__ aaB0, const void* __restrict__ aaB1) {
    __shared__ __align__(16) u16 sXF[3 * 64 * 8];   // 3KB
    __shared__ __align__(16) u16 sHF[4 * 64 * 8];   // 4KB
    const bool isbf = detect_isbf(atom);
    const int t = threadIdx.x, lane = t & 63, w = t >> 6;
    const int quad = lane >> 4;
    const int r0g = blockIdx.x * 16;
    const int mt0 = 2 * w;
    // prefetch AA0 at entry (overlaps the staging global loads)
    uint4 aAA0[2][3]; loadA2<3>(g_Wf + OFF_AA0, mt0, lane, aAA0);
    for (int s = t; s < 3 * 64; s += 256) {
        int lane_s = s & 63, ks = s >> 6;
        int n = lane_s & 15, q = lane_s >> 4;
        *(uint4*)&sXF[s * 8] = pack8(atom, (size_t)(r0g + n) * FA_, FA_, ks * 32 + q * 8, isbf);
    }
    // prefetch AA1 for phase 2 (overlaps barrier)
    uint4 aAA1[2][4]; loadA2<4>(g_Wf + OFF_AA1, mt0, lane, aAA1);
    barrier_lgkm();
    {
        f32x4 bb0 = ldf4(aaB0, mt0 * 16 + quad * 4, isbf);
        f32x4 bb1 = ldf4(aaB0, (mt0 + 1) * 16 + quad * 4, isbf);
        f32x4 acc[2][1];
#pragma unroll
        for (int ii = 0; ii < 2; ++ii) acc[ii][0] = (f32x4){0.f, 0.f, 0.f, 0.f};
        gemm2r<3, 1>(aAA0, sXF, lane, acc);
        EPI_RELU_STORE(acc, bb0, bb1, sHF, 1);
    }
    // prefetch APT/APB for phase 3
    uint4 aAPT[2][3]; loadA2<3>(g_Wf + OFF_APT, mt0, lane, aAPT);
    uint4 aAPB[2][3]; loadA2<3>(g_Wf + OFF_APB, mt0, lane, aAPB);
    barrier_lgkm();
    {
        f32x4 bb0 = ldf4(aaB1, mt0 * 16 + quad * 4, isbf);
        f32x4 bb1 = ldf4(aaB1, (mt0 + 1) * 16 + quad * 4, isbf);
        f32x4 acc[2][1];
#pragma unroll
        for (int ii = 0; ii < 2; ++ii) acc[ii][0] = (f32x4){0.f, 0.f, 0.f, 0.f};
        gemm2r<4, 1>(aAA1, sHF, lane, acc);
        int c = lane & 15;
#pragma unroll
        for (int ii = 0; ii < 2; ++ii) {
            int mt = mt0 + ii;
            f32x4 bb = ii ? bb1 : bb0;
            f32x4 v;
#pragma unroll
            for (int r = 0; r < 4; ++r) { float x = acc[ii][0][r] + bb[r]; v[r] = x > 0.f ? x : 0.f; }
            *(f32x4*)&g_A0[(size_t)(r0g + c) * 128 + mt * 16 + quad * 4] = v;
        }
    }
    {
        // phase 3 reads sXF, untouched since staging -> no extra barrier needed
        f32x4 accT[2][1], accB[2][1];
#pragma unroll
        for (int ii = 0; ii < 2; ++ii) { accT[ii][0] = (f32x4){0.f,0.f,0.f,0.f}; accB[ii][0] = (f32x4){0.f,0.f,0.f,0.f}; }
        gemm2r<3, 1>(aAPT, sXF, lane, accT);
        gemm2r<3, 1>(aAPB, sXF, lane, accB);
        int c = lane & 15;
#pragma unroll
        for (int ii = 0; ii < 2; ++ii) {
            int mt = mt0 + ii;
            size_t row = (size_t)(r0g + c);
            *(f32x4*)&g_TB[row * 256 + mt * 16 + quad * 4] = accT[ii][0];
            *(f32x4*)&g_TB[row * 256 + 128 + mt * 16 + quad * 4] = accB[ii][0];
        }
    }
}

// ---------------- Kernel: atom_layer (512 blocks, 8 rows each) --------------------
// 2 blocks/CU (was 1): the kernel is pure latency chains, so doubling the
// independent block-streams halves wall time. MFMA tiles still span 16 rows;
// rows 8-15 are computed-but-unstored (reads clamped in-bounds).
__global__ __launch_bounds__(256) void atom_layer(
    const void* __restrict__ atom,
    const void* __restrict__ alB0, const void* __restrict__ alB1,
    void* __restrict__ out) {
    __shared__ __align__(16) u16 sXF[8 * 64 * 8];   // 8KB
    __shared__ __align__(16) u16 sHF[4 * 64 * 8];   // 4KB
    const bool isbf = detect_isbf(atom);
    const int t = threadIdx.x, lane = t & 63, w = t >> 6;
    const int quad = lane >> 4;
    const int r0g = blockIdx.x * 8;
    const int mt0 = 2 * w;
    // prefetch AL0 at entry (overlaps the staging global loads)
    uint4 aAL0[2][8]; loadA2<8>(g_Wf + OFF_AL0, mt0, lane, aAL0);
    for (int s = t; s < 8 * 64; s += 256) {
        int lane_s = s & 63, ks = s >> 6;
        int n = lane_s & 15, q = lane_s >> 4;
        int row = r0g + n; if (row > 4095) row = 4095;   // pad rows clamped (unused)
        int k0 = ks * 32 + q * 8;
        const float* src = (k0 < 128) ? &g_A0[(size_t)row * 128 + k0]
                                      : &g_A1[(size_t)row * 128 + (k0 - 128)];
        f32x4 f0 = *(const f32x4*)src, f1 = *(const f32x4*)(src + 4);
        uint4 u;
        u.x = f2bf_pk(f0[0], f0[1]); u.y = f2bf_pk(f0[2], f0[3]);
        u.z = f2bf_pk(f1[0], f1[1]); u.w = f2bf_pk(f1[2], f1[3]);
        *(uint4*)&sXF[s * 8] = u;
    }
    // prefetch AL1 for phase 2 (overlaps barrier)
    uint4 aAL1[2][4]; loadA2<4>(g_Wf + OFF_AL1, mt0, lane, aAL1);
    barrier_lgkm();
    {
        f32x4 bb0 = ldf4(alB0, mt0 * 16 + quad * 4, isbf);
        f32x4 bb1 = ldf4(alB0, (mt0 + 1) * 16 + quad * 4, isbf);
        f32x4 acc[2][1];
#pragma unroll
        for (int ii = 0; ii < 2; ++ii) acc[ii][0] = (f32x4){0.f, 0.f, 0.f, 0.f};
        gemm2r<8, 1>(aAL0, sXF, lane, acc);
        EPI_RELU_STORE(acc, bb0, bb1, sHF, 1);
    }
    barrier_lgkm();
    {
        f32x4 bb0 = ldf4(alB1, mt0 * 16 + quad * 4, isbf);
        f32x4 bb1 = ldf4(alB1, (mt0 + 1) * 16 + quad * 4, isbf);
        f32x4 acc[2][1];
#pragma unroll
        for (int ii = 0; ii < 2; ++ii) acc[ii][0] = (f32x4){0.f, 0.f, 0.f, 0.f};
        gemm2r<4, 1>(aAL1, sHF, lane, acc);
        int c = lane & 15;
        if (c < 8) {
#pragma unroll
            for (int ii = 0; ii < 2; ++ii) {
                int mt = mt0 + ii;
                f32x4 bb = ii ? bb1 : bb0;
                f32x4 v;
#pragma unroll
                for (int r = 0; r < 4; ++r) { float x = acc[ii][0][r] + bb[r]; v[r] = x > 0.f ? x : 0.f; }
                store_out4(out, (size_t)(r0g + c) * 128 + mt * 16 + quad * 4, v, isbf);
            }
        }
    }
}

// ---------------- Kernel: fused pair branch + PairToAtom (4096 blocks) ------------
// R6/R7 best: lgkm barriers + distance-1 weight prefetch + setprio.
__global__ __launch_bounds__(256, 3) void pair_fused(
    const void* __restrict__ atom,
    const void* __restrict__ pairx,
    const void* __restrict__ apB0, const void* __restrict__ apB1,
    const void* __restrict__ ppB0, const void* __restrict__ ppB1,
    const void* __restrict__ plB0, const void* __restrict__ plB1,
    const void* __restrict__ paB0, const void* __restrict__ paB1,
    void* __restrict__ out) {
    __shared__ __align__(16) u16 sX1[4 * 4 * 64 * 8];   // 16KB  H0 -> Hp -> Hl
    __shared__ __align__(16) u16 sX2[4 * 4 * 64 * 8];   // 16KB  H1 -> HpA
    __shared__ __align__(16) u16 sR [4 * 4 * 64 * 8];   // 16KB  P0 -> P1
    __shared__ __align__(16) u16 sPr[4 * 1 * 64 * 8];   // 4KB   pair_x frags
    const bool isbf = detect_isbf(atom);
    const int t = threadIdx.x, lane = t & 63, w = t >> 6;
    const int quad = lane >> 4, c = lane & 15;
    const int bx = blockIdx.x;
    const int b = bx >> 6, i = bx & 63;
    const int trow = b * 64;
    const size_t prow0 = (size_t)b * 4096 + (size_t)i * 64;
    const int mt0 = 2 * w;

    // ---- stage (no barriers yet): Pr frags + H0/H1 built from registers ----
    {
        int lane_s = t & 63, nt = t >> 6;
        int n = nt * 16 + (lane_s & 15), q = lane_s >> 4;
        *(uint4*)&sPr[t * 8] = pack8(pairx, (prow0 + n) * FP_, FP_, q * 8, isbf);
    }
    {
        const int ksg = t >> 6;               // this thread's ks segment
        const int k0 = ksg * 32 + quad * 8;   // fixed 8-wide k window
        const int rc = c;                     // row-class within each 16-row group
        const float* TBi = &g_TB[(size_t)(trow + i) * 256 + k0];
        f32x4 t0 = *(const f32x4*)TBi,        t1 = *(const f32x4*)(TBi + 4);
        f32x4 o0 = *(const f32x4*)(TBi + 128), o1 = *(const f32x4*)(TBi + 132);
        f32x4 b0a = ldf4(apB0, k0, isbf), b0b = ldf4(apB0, k0 + 4, isbf);
        float Tip[8], Bip[8];
#pragma unroll
        for (int r = 0; r < 4; ++r) {
            Tip[r] = t0[r] + b0a[r]; Tip[4 + r] = t1[r] + b0b[r];
            Bip[r] = o0[r] + b0a[r]; Bip[4 + r] = o1[r] + b0b[r];
        }
#pragma unroll
        for (int nt = 0; nt < 4; ++nt) {
            int n = nt * 16 + rc;
            const float* Bj = &g_TB[(size_t)(trow + n) * 256 + k0];
            f32x4 j0 = *(const f32x4*)Bj,        j1 = *(const f32x4*)(Bj + 4);
            f32x4 j2 = *(const f32x4*)(Bj + 128), j3 = *(const f32x4*)(Bj + 132);
            float v0[8], v1[8];
#pragma unroll
            for (int r = 0; r < 4; ++r) {
                float x0 = Tip[r] + j2[r];      v0[r]     = x0 > 0.f ? x0 : 0.f;  // H0
                float x1 = Tip[4 + r] + j3[r];  v0[4 + r] = x1 > 0.f ? x1 : 0.f;
                float y0 = j0[r] + Bip[r];      v1[r]     = y0 > 0.f ? y0 : 0.f;  // H1
                float y1 = j1[r] + Bip[4 + r];  v1[4 + r] = y1 > 0.f ? y1 : 0.f;
            }
            uint4 u0, u1;
            u0.x = f2bf_pk(v0[0], v0[1]); u0.y = f2bf_pk(v0[2], v0[3]);
            u0.z = f2bf_pk(v0[4], v0[5]); u0.w = f2bf_pk(v0[6], v0[7]);
            u1.x = f2bf_pk(v1[0], v1[1]); u1.y = f2bf_pk(v1[2], v1[3]);
            u1.z = f2bf_pk(v1[4], v1[5]); u1.w = f2bf_pk(v1[6], v1[7]);
            int slot = ((nt * 4 + ksg) * 64 + lane) * 8;
            *(uint4*)&sX1[slot] = u0;
            *(uint4*)&sX2[slot] = u1;
        }
    }
    // prefetch phase-C weights (independent of LDS; overlaps barrier)
    uint4 aAP1[2][4]; loadA2<4>(g_Wf + OFF_AP1, mt0, lane, aAP1);
    barrier_lgkm();
    // ---- phase C: P0 = relu(H0@apW1+b1)+relu(H1@apW1+b1) -> sR ;
    //               aH = Pr@ppW0, aPA = Pr@paW0 (regs, carried across barrier) ----
    {
        f32x4 bb0 = ldf4(apB1, mt0 * 16 + quad * 4, isbf);
        f32x4 bb1 = ldf4(apB1, (mt0 + 1) * 16 + quad * 4, isbf);
        f32x4 aA[2][4], aB[2][4];
#pragma unroll
        for (int ii = 0; ii < 2; ++ii)
#pragma unroll
            for (int nt = 0; nt < 4; ++nt) { aA[ii][nt] = (f32x4){0.f,0.f,0.f,0.f}; aB[ii][nt] = (f32x4){0.f,0.f,0.f,0.f}; }
        __builtin_amdgcn_s_setprio(1);
        gemm2r<4, 4>(aAP1, sX1, lane, aA);
        gemm2r<4, 4>(aAP1, sX2, lane, aB);
        __builtin_amdgcn_s_setprio(0);
#pragma unroll
        for (int ii = 0; ii < 2; ++ii) {
            int mt = mt0 + ii;
            f32x4 bb = ii ? bb1 : bb0;
#pragma unroll
            for (int nt = 0; nt < 4; ++nt) {
                f32x4 v;
#pragma unroll
                for (int r = 0; r < 4; ++r) {
                    float x = aA[ii][nt][r] + bb[r];
                    float y = aB[ii][nt][r] + bb[r];
                    v[r] = (x > 0.f ? x : 0.f) + (y > 0.f ? y : 0.f);
                }
                frag_store(sR, 4, nt, mt, lane, v);
            }
        }
    }
    f32x4 aH[2][4], aPA[2][4];
    {
        uint4 aPP0[2][1]; loadA2<1>(g_Wf + OFF_PP0, mt0, lane, aPP0);
        uint4 aPA0[2][1]; loadA2<1>(g_Wf + OFF_PA0, mt0, lane, aPA0);
#pragma unroll
        for (int ii = 0; ii < 2; ++ii)
#pragma unroll
            for (int nt = 0; nt < 4; ++nt) { aH[ii][nt] = (f32x4){0.f,0.f,0.f,0.f}; aPA[ii][nt] = (f32x4){0.f,0.f,0.f,0.f}; }
        gemm2r<1, 4>(aPP0, sPr, lane, aH);
        gemm2r<1, 4>(aPA0, sPr, lane, aPA);
    }
    // prefetch phase-D weights
    uint4 aPL0T[2][4]; loadA2<4>(g_Wf + OFF_PL0T, mt0, lane, aPL0T);
    barrier_lgkm();
    // ---- phase D: C3 = P0@plW0_top ; Hp = relu(aH+b0p) -> sX1 ; HpA = relu(aPA+b0pa) -> sX2
    f32x4 C3[2][4];
#pragma unroll
    for (int ii = 0; ii < 2; ++ii)
#pragma unroll
        for (int nt = 0; nt < 4; ++nt) C3[ii][nt] = (f32x4){0.f, 0.f, 0.f, 0.f};
    __builtin_amdgcn_s_setprio(1);
    gemm2r<4, 4>(aPL0T, sR, lane, C3);
    __builtin_amdgcn_s_setprio(0);
    {
        f32x4 bb0 = ldf4(ppB0, mt0 * 16 + quad * 4, isbf);
        f32x4 bb1 = ldf4(ppB0, (mt0 + 1) * 16 + quad * 4, isbf);
        EPI_RELU_STORE(aH, bb0, bb1, sX1, 4);
    }
    {
        f32x4 bb0 = ldf4(paB0, mt0 * 16 + quad * 4, isbf);
        f32x4 bb1 = ldf4(paB0, (mt0 + 1) * 16 + quad * 4, isbf);
        EPI_RELU_STORE(aPA, bb0, bb1, sX2, 4);
    }
    // prefetch phase-E weights (peak live: C3 + aPP1 + aPA1 ~ 96 regs)
    uint4 aPP1[2][4]; loadA2<4>(g_Wf + OFF_PP1, mt0, lane, aPP1);
    uint4 aPA1[2][4]; loadA2<4>(g_Wf + OFF_PA1, mt0, lane, aPA1);
    barrier_lgkm();
    // ---- phase E: P1 = relu(Hp@ppW1+b1p) -> sR ;
    //               aA1 = HpA@paW1 -> bias/relu/sum over rows -> g_A1 ----
    {
        f32x4 aP[2][4], aA1[2][4];
#pragma unroll
        for (int ii = 0; ii < 2; ++ii)
#pragma unroll
            for (int nt = 0; nt < 4; ++nt) { aP[ii][nt] = (f32x4){0.f,0.f,0.f,0.f}; aA1[ii][nt] = (f32x4){0.f,0.f,0.f,0.f}; }
        __builtin_amdgcn_s_setprio(1);
        gemm2r<4, 4>(aPP1, sX1, lane, aP);
        gemm2r<4, 4>(aPA1, sX2, lane, aA1);
        __builtin_amdgcn_s_setprio(0);
        {
            f32x4 pb0 = ldf4(paB1, mt0 * 16 + quad * 4, isbf);
            f32x4 pb1 = ldf4(paB1, (mt0 + 1) * 16 + quad * 4, isbf);
#pragma unroll
            for (int ii = 0; ii < 2; ++ii) {
                int mt = mt0 + ii;
                f32x4 bb = ii ? pb1 : pb0;
                f32x4 ssum = (f32x4){0.f, 0.f, 0.f, 0.f};
#pragma unroll
                for (int nt = 0; nt < 4; ++nt)
#pragma unroll
                    for (int r = 0; r < 4; ++r) {
                        float x = aA1[ii][nt][r] + bb[r];
                        ssum[r] += (x > 0.f ? x : 0.f);
                    }
#pragma unroll
                for (int m = 1; m < 16; m <<= 1)
#pragma unroll
                    for (int r = 0; r < 4; ++r) ssum[r] += __shfl_xor(ssum[r], m, 64);
                if ((lane & 15) == 0)
                    *(f32x4*)&g_A1[(size_t)bx * 128 + mt * 16 + quad * 4] = ssum;
            }
        }
        f32x4 bb0 = ldf4(ppB1, mt0 * 16 + quad * 4, isbf);
        f32x4 bb1 = ldf4(ppB1, (mt0 + 1) * 16 + quad * 4, isbf);
        EPI_RELU_STORE(aP, bb0, bb1, sR, 4);
    }
    // prefetch phase-F weights
    uint4 aPL0B[2][4]; loadA2<4>(g_Wf + OFF_PL0B, mt0, lane, aPL0B);
    barrier_lgkm();
    // ---- phase F: C3 += P1@plW0_bot ; Hl = relu(C3 + b0l) -> sX1 ----
    __builtin_amdgcn_s_setprio(1);
    gemm2r<4, 4>(aPL0B, sR, lane, C3);
    __builtin_amdgcn_s_setprio(0);
    {
        f32x4 bb0 = ldf4(plB0, mt0 * 16 + quad * 4, isbf);
        f32x4 bb1 = ldf4(plB0, (mt0 + 1) * 16 + quad * 4, isbf);
        EPI_RELU_STORE(C3, bb0, bb1, sX1, 4);
    }
    // prefetch phase-G weights
    uint4 aPL1[2][4]; loadA2<4>(g_Wf + OFF_PL1, mt0, lane, aPL1);
    barrier_lgkm();
    // ---- phase G: out = relu(Hl@plW1 + b1l) ----
    {
        f32x4 bb0 = ldf4(plB1, mt0 * 16 + quad * 4, isbf);
        f32x4 bb1 = ldf4(plB1, (mt0 + 1) * 16 + quad * 4, isbf);
        f32x4 aO[2][4];
#pragma unroll
        for (int ii = 0; ii < 2; ++ii)
#pragma unroll
            for (int nt = 0; nt < 4; ++nt) aO[ii][nt] = (f32x4){0.f, 0.f, 0.f, 0.f};
        __builtin_amdgcn_s_setprio(1);
        gemm2r<4, 4>(aPL1, sX1, lane, aO);
        __builtin_amdgcn_s_setprio(0);
        const size_t NA = (size_t)B_ * N_ * C_;   // 524288
#pragma unroll
        for (int ii = 0; ii < 2; ++ii) {
            int mt = mt0 + ii;
            f32x4 bb = ii ? bb1 : bb0;
#pragma unroll
            for (int nt = 0; nt < 4; ++nt) {
                f32x4 v;
#pragma unroll
                for (int r = 0; r < 4; ++r) { float x = aO[ii][nt][r] + bb[r]; v[r] = x > 0.f ? x : 0.f; }
                store_out4(out, NA + (prow0 + nt * 16 + c) * 128 + mt * 16 + quad * 4, v, isbf);
            }
        }
    }
}

extern "C" void kernel_launch(void* const* d_in, const int* in_sizes, int n_in,
                              void* d_out, int out_size, void* d_ws, size_t ws_size,
                              hipStream_t stream) {
    const void* atom  = d_in[0];
    const void* pairx = d_in[1];
    const void* aaW0 = d_in[2];  const void* aaB0 = d_in[3];
    const void* aaW1 = d_in[4];  const void* aaB1 = d_in[5];
    const void* paW0 = d_in[6];  const void* paB0 = d_in[7];
    const void* paW1 = d_in[8];  const void* paB1 = d_in[9];
    const void* alW0 = d_in[10]; const void* alB0 = d_in[11];
    const void* alW1 = d_in[12]; const void* alB1 = d_in[13];
    const void* apW0 = d_in[14]; const void* apB0 = d_in[15];
    const void* apW1 = d_in[16]; const void* apB1 = d_in[17];
    const void* ppW0 = d_in[18]; const void* ppB0 = d_in[19];
    const void* ppW1 = d_in[20]; const void* ppB1 = d_in[21];
    const void* plW0 = d_in[22]; const void* plB0 = d_in[23];
    const void* plW1 = d_in[24]; const void* plB1 = d_in[25];
    (void)d_ws; (void)ws_size; (void)in_sizes; (void)n_in; (void)out_size;

    prep_w<<<102, 256, 0, stream>>>(atom, aaW0, aaW1, apW0, paW0, paW1, alW0, alW1,
                                    apW1, ppW0, ppW1, plW0, plW1);
    atom_pre<<<256, 256, 0, stream>>>(atom, aaB0, aaB1);
    pair_fused<<<4096, 256, 0, stream>>>(atom, pairx, apB0, apB1, ppB0, ppB1,
                                         plB0, plB1, paB0, paB1, d_out);
    atom_layer<<<512, 256, 0, stream>>>(atom, alB0, alB1, d_out);
}